// Round 16
// baseline (133.267 us; speedup 1.0000x reference)
//
#include <hip/hip_runtime.h>
#include <stdint.h>

#define BATCH 2
#define NH 16
#define SEQ 2048
#define DIM 1024
#define HD 64
#define MROWS (BATCH*SEQ)   // 4096

typedef __attribute__((ext_vector_type(8))) _Float16 f16x8;
typedef __attribute__((ext_vector_type(16))) float f32x16;
typedef __attribute__((ext_vector_type(4))) float f32x4;
typedef __attribute__((ext_vector_type(2))) __fp16 fp16x2;
typedef __attribute__((ext_vector_type(4))) short short4v;
typedef __attribute__((ext_vector_type(2))) unsigned uint2v;

__device__ __forceinline__ short f2h(float f) {
  union { _Float16 h; short s; } u;
  u.h = (_Float16)f;
  return u.s;
}

__device__ __forceinline__ float fast_exp2(float x) {
#if __has_builtin(__builtin_amdgcn_exp2f)
  return __builtin_amdgcn_exp2f(x);
#else
  return exp2f(x);
#endif
}

__device__ __forceinline__ unsigned pk2(float a, float b) {
  union { fp16x2 h; unsigned u; } x;
  x.h = __builtin_amdgcn_cvt_pkrtz(a, b);
  return x.u;
}

// a.hi(lanes32-63) <-> b.lo(lanes0-31).
__device__ __forceinline__ void perm32swap(unsigned &a, unsigned &b) {
#if __has_builtin(__builtin_amdgcn_permlane32_swap)
  uint2v r = __builtin_amdgcn_permlane32_swap(a, b, false, false);  // VALU op
  a = r[0]; b = r[1];
#else
  unsigned as = (unsigned)__shfl_xor((int)a, 32);
  unsigned bs = (unsigned)__shfl_xor((int)b, 32);
  bool lo = ((threadIdx.x & 63) < 32);
  unsigned na = lo ? a : bs;
  unsigned nb = lo ? as : b;
  a = na; b = nb;
#endif
}

__device__ __forceinline__ void async_load16(const void* g, void* l) {
  __builtin_amdgcn_global_load_lds((const __attribute__((address_space(1))) void*)g,
                                   (__attribute__((address_space(3))) void*)l, 16, 0, 0);
}

// ---------------- convert f32 -> f16 ----------------
__global__ __launch_bounds__(256) void k_cvt(const float* __restrict__ in,
                                             short* __restrict__ out, int n4) {
  int i = blockIdx.x * 256 + threadIdx.x;
  if (i >= n4) return;
  float4 v = ((const float4*)in)[i];
  short4v o;
  o[0] = f2h(v.x); o[1] = f2h(v.y); o[2] = f2h(v.z); o[3] = f2h(v.w);
  ((short4v*)out)[i] = o;
}

// ---------------- transpose (K x N) f32 -> (N x K) f16 ----------------
__global__ __launch_bounds__(256) void k_transpose(const float* __restrict__ in,
                                                   short* __restrict__ out,
                                                   int K, int N) {
  __shared__ float t[32][33];
  int n0 = blockIdx.x * 32, k0 = blockIdx.y * 32;
  int tx = threadIdx.x, ty = threadIdx.y;  // 32 x 8
  #pragma unroll
  for (int i = 0; i < 32; i += 8)
    t[ty + i][tx] = in[(size_t)(k0 + ty + i) * N + (n0 + tx)];
  __syncthreads();
  #pragma unroll
  for (int i = 0; i < 32; i += 8)
    out[(size_t)(n0 + ty + i) * K + (k0 + tx)] = f2h(t[tx][ty + i]);
}

// ---------------- GEMM  C[M,N] = A[M,K] * Bt[N,K]^T  (fp16 in, f32 acc) ---
// BK=64, double-buffered LDS, counted vmcnt, XOR-swizzle (rule #21 pattern).
// MODE 0 (BM=128): QKV epilogue; MODE 1 (BM=64): f32 output + bias
template <int MODE, int BM>
__global__ __launch_bounds__(256) void k_gemm_bt(
    const short* __restrict__ A, const short* __restrict__ Bt,
    const float* __restrict__ bias,
    short* __restrict__ Qd, short* __restrict__ Kd, short* __restrict__ Vtd,
    float* __restrict__ Cf, int Ncols, int Kdim) {
  constexpr int BN = 128, BK = 64;
  constexpr int RI = BM / 32;            // row fragments per wave
  __shared__ short Al[2][BM * BK];
  __shared__ short Bl[2][BN * BK];
  const int tid = threadIdx.x;
  const int lane = tid & 63;
  const int wid = tid >> 6;
  const int wr = wid >> 1, wc = wid & 1;
  const int m0 = blockIdx.y * BM, n0 = blockIdx.x * BN;
  const int l15 = lane & 15, lk = (lane >> 4) * 8;

  f32x4 acc[RI][4] = {};

  auto stage = [&](int kt, int buf) {
    int k0 = kt * BK;
    #pragma unroll
    for (int i2 = 0; i2 < BM / 32; i2++) {
      int c = i2 * 256 + tid;
      int r = c >> 3, cs = (c & 7) * 8;
      async_load16(A + (size_t)(m0 + r) * Kdim + k0 + (cs ^ ((r & 7) * 8)),
                   &Al[buf][c * 8]);
    }
    #pragma unroll
    for (int i2 = 0; i2 < 4; i2++) {
      int c = i2 * 256 + tid;
      int r = c >> 3, cs = (c & 7) * 8;
      async_load16(Bt + (size_t)(n0 + r) * Kdim + k0 + (cs ^ ((r & 7) * 8)),
                   &Bl[buf][c * 8]);
    }
  };

  auto compute = [&](int buf) {
    f16x8 af[2][RI], bfr[2][4];
    #pragma unroll
    for (int kk = 0; kk < 2; kk++) {
      #pragma unroll
      for (int i = 0; i < RI; i++) {
        int row = wr * (BM / 2) + i * 16 + l15;
        af[kk][i] = *(const f16x8*)&Al[buf][row * 64 + ((kk * 32 + lk) ^ ((row & 7) * 8))];
      }
      #pragma unroll
      for (int j = 0; j < 4; j++) {
        int row = wc * 64 + j * 16 + l15;
        bfr[kk][j] = *(const f16x8*)&Bl[buf][row * 64 + ((kk * 32 + lk) ^ ((row & 7) * 8))];
      }
    }
    __builtin_amdgcn_s_setprio(1);
    #pragma unroll
    for (int i = 0; i < RI; i++)
      #pragma unroll
      for (int j = 0; j < 4; j++) {
        acc[i][j] = __builtin_amdgcn_mfma_f32_16x16x32_f16(af[0][i], bfr[0][j], acc[i][j], 0, 0, 0);
        acc[i][j] = __builtin_amdgcn_mfma_f32_16x16x32_f16(af[1][i], bfr[1][j], acc[i][j], 0, 0, 0);
      }
    __builtin_amdgcn_s_setprio(0);
  };

  stage(0, 0);
  const int NT = Kdim / BK;
  for (int t = 0; t < NT; t++) {
    int cur = t & 1;
    if (t + 1 < NT) {
      stage(t + 1, cur ^ 1);
      if constexpr (BM == 128) asm volatile("s_waitcnt vmcnt(8)" ::: "memory");
      else                     asm volatile("s_waitcnt vmcnt(6)" ::: "memory");
    } else {
      asm volatile("s_waitcnt vmcnt(0)" ::: "memory");
    }
    __builtin_amdgcn_s_barrier();
    __builtin_amdgcn_sched_barrier(0);
    compute(cur);
    __builtin_amdgcn_sched_barrier(0);
    __builtin_amdgcn_s_barrier();
  }

  const int rl = (lane >> 4) * 4;
  if (MODE == 0) {
    #pragma unroll
    for (int j = 0; j < 4; j++) {
      int col = n0 + wc * 64 + j * 16 + l15;
      float bv = bias[col];
      int sec = col >> 10;          // 0=Q 1=K 2=V
      int cc = col & 1023;
      int h = cc >> 6, hd = cc & 63;
      float mul = (sec == 0) ? (0.125f * 1.44269504088896f) : 1.0f;
      #pragma unroll
      for (int i = 0; i < RI; i++) {
        int rowb = m0 + wr * (BM / 2) + i * 16 + rl;
        #pragma unroll
        for (int r = 0; r < 4; r++) {
          int row = rowb + r;
          int b = row >> 11, nr = row & 2047;
          short v = f2h((acc[i][j][r] + bv) * mul);
          size_t bh = (size_t)(b * NH + h);
          size_t base2 = bh * (size_t)(SEQ * HD);
          if (sec == 0) {
            Qd[base2 + (size_t)nr * HD + hd] = v;
          } else if (sec == 1) {
            // K A-frag layout
            Kd[base2 + (size_t)(((nr >> 5) * 4 + (hd >> 4)) * 512 +
                                (((hd >> 3) & 1) * 32 + (nr & 31)) * 8 + (hd & 7))] = v;
          } else {
            // V B-frag layout
            Vtd[base2 + (size_t)(((nr >> 4) * 2 + (hd >> 5)) * 512 +
                                 (((nr >> 3) & 1) * 32 + (hd & 31)) * 8 + (nr & 7))] = v;
          }
        }
      }
    }
  } else {
    #pragma unroll
    for (int j = 0; j < 4; j++) {
      int col = n0 + wc * 64 + j * 16 + l15;
      float bv = bias[col];
      #pragma unroll
      for (int i = 0; i < RI; i++) {
        int rowb = m0 + wr * (BM / 2) + i * 16 + rl;
        #pragma unroll
        for (int r = 0; r < 4; r++)
          Cf[(size_t)(rowb + r) * Ncols + col] = acc[i][j][r] + bv;
      }
    }
  }
}

// ---------------- flash attention v8: L2-direct + independent tile pipes -
// Same as v7 (no LDS main loop, fragment-major L2-direct loads) but the two
// tiles of each ping-pong pair now have INDEPENDENT named accumulators
// (oA0/oA1 vs oB0/oB1) so QK_B overlaps PACK_A, PV_A overlaps PACK_B —
// the MFMA and VALU/trans pipes interleave within one wave (T15). The
// cross-tile o-dependency chain halves. Merged once at the end.
#define QBLK 64
#define NKVT (SEQ / 64)

#define PACK8(sv, R0, lsv, OUT) do {                                        \
    float e0_ = fast_exp2((sv)[R0 + 0]), e1_ = fast_exp2((sv)[R0 + 1]);     \
    float e2_ = fast_exp2((sv)[R0 + 2]), e3_ = fast_exp2((sv)[R0 + 3]);     \
    float e4_ = fast_exp2((sv)[R0 + 4]), e5_ = fast_exp2((sv)[R0 + 5]);     \
    float e6_ = fast_exp2((sv)[R0 + 6]), e7_ = fast_exp2((sv)[R0 + 7]);     \
    lsv += ((e0_ + e1_) + (e2_ + e3_)) + ((e4_ + e5_) + (e6_ + e7_));       \
    unsigned u0_ = pk2(e0_, e1_), u1_ = pk2(e2_, e3_);                      \
    unsigned u2_ = pk2(e4_, e5_), u3_ = pk2(e6_, e7_);                      \
    perm32swap(u0_, u2_);                                                   \
    perm32swap(u1_, u3_);                                                   \
    union { unsigned u[4]; f16x8 v; } W_;                                   \
    W_.u[0] = u0_; W_.u[1] = u1_; W_.u[2] = u2_; W_.u[3] = u3_;             \
    OUT = W_.v;                                                             \
  } while (0)

__global__ __launch_bounds__(256) void k_flash(const short* __restrict__ Qd,
                                               const short* __restrict__ KB,
                                               const short* __restrict__ VB,
                                               short* __restrict__ Od) {
  __shared__ float ob[4096];   // merge: 2 q-tiles x 2048 floats (16 KB)
  __shared__ float lb[128];
  const int tid = threadIdx.x;
  const int lane = tid & 63;
  const int w = tid >> 6;
  const int wq = w >> 1;             // q-tile within block (0,1)
  const int kvh = w & 1;             // kv half of each tile (0,1)
  const int l31 = lane & 31, lh = lane >> 5;
  const int bh = blockIdx.x;
  const int q0 = blockIdx.y * QBLK + wq * 32;
  const size_t base = (size_t)bh * (size_t)(SEQ * HD);

  // Q fragments (B-operand): col q = l31, k = d = ds*16 + lh*8 + i
  f16x8 qf[4];
  #pragma unroll
  for (int ds = 0; ds < 4; ds++)
    qf[ds] = *(const f16x8*)(Qd + base + (size_t)(q0 + l31) * HD + ds * 16 + lh * 8);

  // wave-uniform fragment bases (this wave's kv-half folded in)
  const short* kb = KB + base + kvh * 2048 + (size_t)lane * 8;
  const short* vb = VB + base + kvh * 2048 + (size_t)lane * 8;

  // independent per-parity accumulators (named: rule #20)
  f32x16 oA0 = {}, oA1 = {}, oB0 = {}, oB1 = {};
  float lsum = 0.f;

#define LOADK(t, kf) do {                                                   \
    const short* p_ = kb + (size_t)(t) * 4096;                              \
    kf[0] = *(const f16x8*)(p_);                                            \
    kf[1] = *(const f16x8*)(p_ + 512);                                      \
    kf[2] = *(const f16x8*)(p_ + 1024);                                     \
    kf[3] = *(const f16x8*)(p_ + 1536);                                     \
  } while (0)
#define LOADV(t, vf) do {                                                   \
    const short* p_ = vb + (size_t)(t) * 4096;                              \
    vf[0] = *(const f16x8*)(p_);            /* ks0 hd0 */                   \
    vf[1] = *(const f16x8*)(p_ + 512);      /* ks0 hd1 */                   \
    vf[2] = *(const f16x8*)(p_ + 1024);     /* ks1 hd0 */                   \
    vf[3] = *(const f16x8*)(p_ + 1536);     /* ks1 hd1 */                   \
  } while (0)

  f16x8 kA[4], vA[4], kB_[4], vB_[4];
  LOADK(0, kA); LOADV(0, vA);
  for (int t = 0; t < NKVT; t += 2) {
    LOADK(t + 1, kB_); LOADV(t + 1, vB_);
    // ---- QK for both tiles first (independent MFMA chains) ----
    f32x16 sA = {}, sB = {};
    __builtin_amdgcn_s_setprio(1);
    #pragma unroll
    for (int ds = 0; ds < 4; ds++)
      sA = __builtin_amdgcn_mfma_f32_32x32x16_f16(kA[ds], qf[ds], sA, 0, 0, 0);
    #pragma unroll
    for (int ds = 0; ds < 4; ds++)
      sB = __builtin_amdgcn_mfma_f32_32x32x16_f16(kB_[ds], qf[ds], sB, 0, 0, 0);
    __builtin_amdgcn_s_setprio(0);
    // ---- PACK_A (VALU/trans) overlaps sB's MFMA latency ----
    f16x8 pA[2];
    PACK8(sA, 0, lsum, pA[0]); PACK8(sA, 8, lsum, pA[1]);
    // ---- PV_A into oA (MFMA) — overlaps PACK_B below ----
    __builtin_amdgcn_s_setprio(1);
    #pragma unroll
    for (int ks = 0; ks < 2; ks++) {
      oA0 = __builtin_amdgcn_mfma_f32_32x32x16_f16(pA[ks], vA[ks * 2 + 0], oA0, 0, 0, 0);
      oA1 = __builtin_amdgcn_mfma_f32_32x32x16_f16(pA[ks], vA[ks * 2 + 1], oA1, 0, 0, 0);
    }
    __builtin_amdgcn_s_setprio(0);
    // prefetch next pair's A-tile under PACK_B/PV_B
    if (t + 2 < NKVT) { LOADK(t + 2, kA); LOADV(t + 2, vA); }
    // ---- PACK_B + PV_B into oB (independent of A path) ----
    f16x8 pB[2];
    PACK8(sB, 0, lsum, pB[0]); PACK8(sB, 8, lsum, pB[1]);
    __builtin_amdgcn_s_setprio(1);
    #pragma unroll
    for (int ks = 0; ks < 2; ks++) {
      oB0 = __builtin_amdgcn_mfma_f32_32x32x16_f16(pB[ks], vB_[ks * 2 + 0], oB0, 0, 0, 0);
      oB1 = __builtin_amdgcn_mfma_f32_32x32x16_f16(pB[ks], vB_[ks * 2 + 1], oB1, 0, 0, 0);
    }
    __builtin_amdgcn_s_setprio(0);
  }
#undef LOADK
#undef LOADV

  // fold parity accumulators
  f32x16 o0 = oA0 + oB0;
  f32x16 o1 = oA1 + oB1;

  // ---- merge kv halves (exact: unnormalized O and lsum add) ----
  if (kvh == 1) {
    #pragma unroll
    for (int rq = 0; rq < 4; rq++) {
      f32x4 v4;
      v4[0] = o0[rq * 4 + 0]; v4[1] = o0[rq * 4 + 1];
      v4[2] = o0[rq * 4 + 2]; v4[3] = o0[rq * 4 + 3];
      *(f32x4*)&ob[wq * 2048 + rq * 256 + lane * 4] = v4;
      f32x4 w4;
      w4[0] = o1[rq * 4 + 0]; w4[1] = o1[rq * 4 + 1];
      w4[2] = o1[rq * 4 + 2]; w4[3] = o1[rq * 4 + 3];
      *(f32x4*)&ob[wq * 2048 + (4 + rq) * 256 + lane * 4] = w4;
    }
    lb[wq * 64 + lane] = lsum;
  }
  __syncthreads();
  if (kvh == 0) {
    #pragma unroll
    for (int rq = 0; rq < 4; rq++) {
      f32x4 v4 = *(const f32x4*)&ob[wq * 2048 + rq * 256 + lane * 4];
      o0[rq * 4 + 0] += v4[0]; o0[rq * 4 + 1] += v4[1];
      o0[rq * 4 + 2] += v4[2]; o0[rq * 4 + 3] += v4[3];
      f32x4 w4 = *(const f32x4*)&ob[wq * 2048 + (4 + rq) * 256 + lane * 4];
      o1[rq * 4 + 0] += w4[0]; o1[rq * 4 + 1] += w4[1];
      o1[rq * 4 + 2] += w4[2]; o1[rq * 4 + 3] += w4[3];
    }
    lsum += lb[wq * 64 + lane];

    lsum += __shfl_xor(lsum, 32);
    float inv = 1.f / lsum;
    const int b = bh >> 4, h = bh & 15;
    #pragma unroll
    for (int reg = 0; reg < 16; reg++) {
      int qrow = (reg & 3) + 8 * (reg >> 2) + 4 * lh;
      float s = __shfl(inv, qrow);
      size_t r0 = (size_t)(b * SEQ + q0 + qrow) * DIM + h * 64;
      Od[r0 + l31]      = f2h(o0[reg] * s);
      Od[r0 + 32 + l31] = f2h(o1[reg] * s);
    }
  }
}

extern "C" void kernel_launch(void* const* d_in, const int* in_sizes, int n_in,
                              void* d_out, int out_size, void* d_ws, size_t ws_size,
                              hipStream_t stream) {
  const float* x     = (const float*)d_in[0];
  const float* Wqkv  = (const float*)d_in[1];
  const float* bqkv  = (const float*)d_in[2];
  const float* Wproj = (const float*)d_in[3];
  const float* bproj = (const float*)d_in[4];
  float* out = (float*)d_out;

  char* ws = (char*)d_ws;                       // needs 48 MB
  short* x_h    = (short*)(ws);                 //  8 MB  x as f16
  short* Wqkv_t = (short*)(ws + ((size_t)8  << 20));  // 6 MB
  short* Wproj_t= (short*)(ws + ((size_t)14 << 20));  // 2 MB
  short* Qd     = (short*)(ws + ((size_t)16 << 20));  // 8 MB (bh, n, hd)
  short* Kd     = (short*)(ws + ((size_t)24 << 20));  // 8 MB K fragment-major
  short* Vtd    = (short*)(ws + ((size_t)32 << 20));  // 8 MB V fragment-major
  short* Od     = (short*)(ws + ((size_t)40 << 20));  // 8 MB

  // 1. x -> f16
  k_cvt<<<(MROWS * DIM / 4 + 255) / 256, 256, 0, stream>>>(x, x_h, MROWS * DIM / 4);
  // 2. weights -> transposed f16 (N x K)
  dim3 tb(32, 8);
  k_transpose<<<dim3(3 * DIM / 32, DIM / 32), tb, 0, stream>>>(Wqkv, Wqkv_t, DIM, 3 * DIM);
  k_transpose<<<dim3(DIM / 32, DIM / 32), tb, 0, stream>>>(Wproj, Wproj_t, DIM, DIM);
  // 3. QKV GEMM + split/fragment epilogue (BM=128)
  k_gemm_bt<0, 128><<<dim3(3 * DIM / 128, MROWS / 128), 256, 0, stream>>>(
      x_h, Wqkv_t, bqkv, Qd, Kd, Vtd, nullptr, 3 * DIM, DIM);
  // 4. flash attention (L2-direct, independent tile pipes, 1024 blocks)
  k_flash<<<dim3(BATCH * NH, SEQ / QBLK), 256, 0, stream>>>(Qd, Kd, Vtd, Od);
  // 5. proj GEMM -> f32 out (BM=64: 512 blocks = 2/CU)
  k_gemm_bt<1, 64><<<dim3(DIM / 128, MROWS / 64), 256, 0, stream>>>(
      Od, Wproj_t, bproj, nullptr, nullptr, nullptr, out, DIM, DIM);
}

// Round 19
// 132.084 us; speedup vs baseline: 1.0090x; 1.0090x over previous
//
#include <hip/hip_runtime.h>
#include <stdint.h>

#define BATCH 2
#define NH 16
#define SEQ 2048
#define DIM 1024
#define HD 64
#define MROWS (BATCH*SEQ)   // 4096

typedef __attribute__((ext_vector_type(8))) _Float16 f16x8;
typedef __attribute__((ext_vector_type(16))) float f32x16;
typedef __attribute__((ext_vector_type(4))) float f32x4;
typedef __attribute__((ext_vector_type(2))) __fp16 fp16x2;
typedef __attribute__((ext_vector_type(4))) short short4v;
typedef __attribute__((ext_vector_type(2))) unsigned uint2v;

__device__ __forceinline__ short f2h(float f) {
  union { _Float16 h; short s; } u;
  u.h = (_Float16)f;
  return u.s;
}

__device__ __forceinline__ float fast_exp2(float x) {
#if __has_builtin(__builtin_amdgcn_exp2f)
  return __builtin_amdgcn_exp2f(x);
#else
  return exp2f(x);
#endif
}

__device__ __forceinline__ unsigned pk2(float a, float b) {
  union { fp16x2 h; unsigned u; } x;
  x.h = __builtin_amdgcn_cvt_pkrtz(a, b);
  return x.u;
}

// a.hi(lanes32-63) <-> b.lo(lanes0-31).
__device__ __forceinline__ void perm32swap(unsigned &a, unsigned &b) {
#if __has_builtin(__builtin_amdgcn_permlane32_swap)
  uint2v r = __builtin_amdgcn_permlane32_swap(a, b, false, false);  // VALU op
  a = r[0]; b = r[1];
#else
  unsigned as = (unsigned)__shfl_xor((int)a, 32);
  unsigned bs = (unsigned)__shfl_xor((int)b, 32);
  bool lo = ((threadIdx.x & 63) < 32);
  unsigned na = lo ? a : bs;
  unsigned nb = lo ? as : b;
  a = na; b = nb;
#endif
}

__device__ __forceinline__ void async_load16(const void* g, void* l) {
  __builtin_amdgcn_global_load_lds((const __attribute__((address_space(1))) void*)g,
                                   (__attribute__((address_space(3))) void*)l, 16, 0, 0);
}

// ---------------- convert f32 -> f16 ----------------
__global__ __launch_bounds__(256) void k_cvt(const float* __restrict__ in,
                                             short* __restrict__ out, int n4) {
  int i = blockIdx.x * 256 + threadIdx.x;
  if (i >= n4) return;
  float4 v = ((const float4*)in)[i];
  short4v o;
  o[0] = f2h(v.x); o[1] = f2h(v.y); o[2] = f2h(v.z); o[3] = f2h(v.w);
  ((short4v*)out)[i] = o;
}

// ---------------- transpose (K x N) f32 -> (N x K) f16 ----------------
__global__ __launch_bounds__(256) void k_transpose(const float* __restrict__ in,
                                                   short* __restrict__ out,
                                                   int K, int N) {
  __shared__ float t[32][33];
  int n0 = blockIdx.x * 32, k0 = blockIdx.y * 32;
  int tx = threadIdx.x, ty = threadIdx.y;  // 32 x 8
  #pragma unroll
  for (int i = 0; i < 32; i += 8)
    t[ty + i][tx] = in[(size_t)(k0 + ty + i) * N + (n0 + tx)];
  __syncthreads();
  #pragma unroll
  for (int i = 0; i < 32; i += 8)
    out[(size_t)(n0 + ty + i) * K + (k0 + tx)] = f2h(t[tx][ty + i]);
}

// ---------------- GEMM  C[M,N] = A[M,K] * Bt[N,K]^T  (fp16 in, f32 acc) ---
// BK=64, double-buffered LDS, counted vmcnt, XOR-swizzle (rule #21 pattern),
// T1 chunked XCD block swizzle (each XCD owns a contiguous 2D tile region).
// MODE 0 (BM=128, grid 24x32): QKV epilogue; MODE 1 (BM=64, grid 8x64): f32+bias
template <int MODE, int BM>
__global__ __launch_bounds__(256) void k_gemm_bt(
    const short* __restrict__ A, const short* __restrict__ Bt,
    const float* __restrict__ bias,
    short* __restrict__ Qd, short* __restrict__ Kd, short* __restrict__ Vtd,
    float* __restrict__ Cf, int Ncols, int Kdim) {
  constexpr int BN = 128, BK = 64;
  constexpr int RI = BM / 32;            // row fragments per wave
  __shared__ short Al[2][BM * BK];
  __shared__ short Bl[2][BN * BK];
  const int tid = threadIdx.x;
  const int lane = tid & 63;
  const int wid = tid >> 6;
  const int wr = wid >> 1, wc = wid & 1;
  // T1: chunked XCD swizzle. XCD = lin%8; each XCD gets a contiguous chunk.
  const int lin = blockIdx.y * (int)gridDim.x + blockIdx.x;
  const int xcd = lin & 7, loc = lin >> 3;
  int bx, by;
  if (MODE == 0) { bx = (xcd & 1) * 12 + loc % 12; by = (xcd >> 1) * 8 + loc / 12; }
  else           { bx = loc % 8;                   by = xcd * 8 + loc / 8; }
  const int m0 = by * BM, n0 = bx * BN;
  const int l15 = lane & 15, lk = (lane >> 4) * 8;

  f32x4 acc[RI][4] = {};

  auto stage = [&](int kt, int buf) {
    int k0 = kt * BK;
    #pragma unroll
    for (int i2 = 0; i2 < BM / 32; i2++) {
      int c = i2 * 256 + tid;
      int r = c >> 3, cs = (c & 7) * 8;
      async_load16(A + (size_t)(m0 + r) * Kdim + k0 + (cs ^ ((r & 7) * 8)),
                   &Al[buf][c * 8]);
    }
    #pragma unroll
    for (int i2 = 0; i2 < 4; i2++) {
      int c = i2 * 256 + tid;
      int r = c >> 3, cs = (c & 7) * 8;
      async_load16(Bt + (size_t)(n0 + r) * Kdim + k0 + (cs ^ ((r & 7) * 8)),
                   &Bl[buf][c * 8]);
    }
  };

  auto compute = [&](int buf) {
    f16x8 af[2][RI], bfr[2][4];
    #pragma unroll
    for (int kk = 0; kk < 2; kk++) {
      #pragma unroll
      for (int i = 0; i < RI; i++) {
        int row = wr * (BM / 2) + i * 16 + l15;
        af[kk][i] = *(const f16x8*)&Al[buf][row * 64 + ((kk * 32 + lk) ^ ((row & 7) * 8))];
      }
      #pragma unroll
      for (int j = 0; j < 4; j++) {
        int row = wc * 64 + j * 16 + l15;
        bfr[kk][j] = *(const f16x8*)&Bl[buf][row * 64 + ((kk * 32 + lk) ^ ((row & 7) * 8))];
      }
    }
    __builtin_amdgcn_s_setprio(1);
    #pragma unroll
    for (int i = 0; i < RI; i++)
      #pragma unroll
      for (int j = 0; j < 4; j++) {
        acc[i][j] = __builtin_amdgcn_mfma_f32_16x16x32_f16(af[0][i], bfr[0][j], acc[i][j], 0, 0, 0);
        acc[i][j] = __builtin_amdgcn_mfma_f32_16x16x32_f16(af[1][i], bfr[1][j], acc[i][j], 0, 0, 0);
      }
    __builtin_amdgcn_s_setprio(0);
  };

  stage(0, 0);
  const int NT = Kdim / BK;
  for (int t = 0; t < NT; t++) {
    int cur = t & 1;
    if (t + 1 < NT) {
      stage(t + 1, cur ^ 1);
      if constexpr (BM == 128) asm volatile("s_waitcnt vmcnt(8)" ::: "memory");
      else                     asm volatile("s_waitcnt vmcnt(6)" ::: "memory");
    } else {
      asm volatile("s_waitcnt vmcnt(0)" ::: "memory");
    }
    __builtin_amdgcn_s_barrier();
    __builtin_amdgcn_sched_barrier(0);
    compute(cur);
    __builtin_amdgcn_sched_barrier(0);
    __builtin_amdgcn_s_barrier();
  }

  const int rl = (lane >> 4) * 4;
  if (MODE == 0) {
    #pragma unroll
    for (int j = 0; j < 4; j++) {
      int col = n0 + wc * 64 + j * 16 + l15;
      float bv = bias[col];
      int sec = col >> 10;          // 0=Q 1=K 2=V
      int cc = col & 1023;
      int h = cc >> 6, hd = cc & 63;
      float mul = (sec == 0) ? (0.125f * 1.44269504088896f) : 1.0f;
      #pragma unroll
      for (int i = 0; i < RI; i++) {
        int rowb = m0 + wr * (BM / 2) + i * 16 + rl;
        #pragma unroll
        for (int r = 0; r < 4; r++) {
          int row = rowb + r;
          int b = row >> 11, nr = row & 2047;
          short v = f2h((acc[i][j][r] + bv) * mul);
          size_t bh = (size_t)(b * NH + h);
          size_t base2 = bh * (size_t)(SEQ * HD);
          if (sec == 0) {
            Qd[base2 + (size_t)nr * HD + hd] = v;
          } else if (sec == 1) {
            // K A-frag layout
            Kd[base2 + (size_t)(((nr >> 5) * 4 + (hd >> 4)) * 512 +
                                (((hd >> 3) & 1) * 32 + (nr & 31)) * 8 + (hd & 7))] = v;
          } else {
            // V B-frag layout
            Vtd[base2 + (size_t)(((nr >> 4) * 2 + (hd >> 5)) * 512 +
                                 (((nr >> 3) & 1) * 32 + (hd & 31)) * 8 + (nr & 7))] = v;
          }
        }
      }
    }
  } else {
    #pragma unroll
    for (int j = 0; j < 4; j++) {
      int col = n0 + wc * 64 + j * 16 + l15;
      float bv = bias[col];
      #pragma unroll
      for (int i = 0; i < RI; i++) {
        int rowb = m0 + wr * (BM / 2) + i * 16 + rl;
        #pragma unroll
        for (int r = 0; r < 4; r++)
          Cf[(size_t)(rowb + r) * Ncols + col] = acc[i][j][r] + bv;
      }
    }
  }
}

// ---------------- flash attention v9: L2-direct, strength-reduced addrs ---
// v8 structure (independent tile-pair accumulators) but the 16 loads per
// pair now come from 4 advancing base pointers (+16 KB per pair) with
// immediate offsets <= 3072 B — removes the per-load 64-bit address
// materialization that inflated VALUBusy.
#define QBLK 64
#define NKVT (SEQ / 64)

#define PACK8(sv, R0, lsv, OUT) do {                                        \
    float e0_ = fast_exp2((sv)[R0 + 0]), e1_ = fast_exp2((sv)[R0 + 1]);     \
    float e2_ = fast_exp2((sv)[R0 + 2]), e3_ = fast_exp2((sv)[R0 + 3]);     \
    float e4_ = fast_exp2((sv)[R0 + 4]), e5_ = fast_exp2((sv)[R0 + 5]);     \
    float e6_ = fast_exp2((sv)[R0 + 6]), e7_ = fast_exp2((sv)[R0 + 7]);     \
    lsv += ((e0_ + e1_) + (e2_ + e3_)) + ((e4_ + e5_) + (e6_ + e7_));       \
    unsigned u0_ = pk2(e0_, e1_), u1_ = pk2(e2_, e3_);                      \
    unsigned u2_ = pk2(e4_, e5_), u3_ = pk2(e6_, e7_);                      \
    perm32swap(u0_, u2_);                                                   \
    perm32swap(u1_, u3_);                                                   \
    union { unsigned u[4]; f16x8 v; } W_;                                   \
    W_.u[0] = u0_; W_.u[1] = u1_; W_.u[2] = u2_; W_.u[3] = u3_;             \
    OUT = W_.v;                                                             \
  } while (0)

#define LOADF(pt, fr) do {                                                  \
    fr[0] = *(const f16x8*)(pt);                                            \
    fr[1] = *(const f16x8*)((pt) + 512);                                    \
    fr[2] = *(const f16x8*)((pt) + 1024);                                   \
    fr[3] = *(const f16x8*)((pt) + 1536);                                   \
  } while (0)

__global__ __launch_bounds__(256) void k_flash(const short* __restrict__ Qd,
                                               const short* __restrict__ KB,
                                               const short* __restrict__ VB,
                                               short* __restrict__ Od) {
  __shared__ float ob[4096];   // merge: 2 q-tiles x 2048 floats (16 KB)
  __shared__ float lb[128];
  const int tid = threadIdx.x;
  const int lane = tid & 63;
  const int w = tid >> 6;
  const int wq = w >> 1;             // q-tile within block (0,1)
  const int kvh = w & 1;             // kv half of each tile (0,1)
  const int l31 = lane & 31, lh = lane >> 5;
  const int bh = blockIdx.x;
  const int q0 = blockIdx.y * QBLK + wq * 32;
  const size_t base = (size_t)bh * (size_t)(SEQ * HD);

  // Q fragments (B-operand): col q = l31, k = d = ds*16 + lh*8 + i
  f16x8 qf[4];
  #pragma unroll
  for (int ds = 0; ds < 4; ds++)
    qf[ds] = *(const f16x8*)(Qd + base + (size_t)(q0 + l31) * HD + ds * 16 + lh * 8);

  // advancing fragment base pointers (even tile / odd tile), +8192 per pair
  const short* kp0 = KB + base + kvh * 2048 + (size_t)lane * 8;
  const short* kp1 = kp0 + 4096;
  const short* vp0 = VB + base + kvh * 2048 + (size_t)lane * 8;
  const short* vp1 = vp0 + 4096;

  // independent per-parity accumulators (named: rule #20)
  f32x16 oA0 = {}, oA1 = {}, oB0 = {}, oB1 = {};
  float lsum = 0.f;

  f16x8 kA[4], vA[4], kB_[4], vB_[4];
  LOADF(kp0, kA); LOADF(vp0, vA);
  for (int t = 0; t < NKVT; t += 2) {
    LOADF(kp1, kB_); LOADF(vp1, vB_);
    kp1 += 8192; vp1 += 8192;
    // ---- QK for both tiles first (independent MFMA chains) ----
    f32x16 sA = {}, sB = {};
    __builtin_amdgcn_s_setprio(1);
    #pragma unroll
    for (int ds = 0; ds < 4; ds++)
      sA = __builtin_amdgcn_mfma_f32_32x32x16_f16(kA[ds], qf[ds], sA, 0, 0, 0);
    #pragma unroll
    for (int ds = 0; ds < 4; ds++)
      sB = __builtin_amdgcn_mfma_f32_32x32x16_f16(kB_[ds], qf[ds], sB, 0, 0, 0);
    __builtin_amdgcn_s_setprio(0);
    // ---- PACK_A (VALU/trans) overlaps sB's MFMA latency ----
    f16x8 pA[2];
    PACK8(sA, 0, lsum, pA[0]); PACK8(sA, 8, lsum, pA[1]);
    // ---- PV_A into oA (MFMA) — overlaps PACK_B below ----
    __builtin_amdgcn_s_setprio(1);
    #pragma unroll
    for (int ks = 0; ks < 2; ks++) {
      oA0 = __builtin_amdgcn_mfma_f32_32x32x16_f16(pA[ks], vA[ks * 2 + 0], oA0, 0, 0, 0);
      oA1 = __builtin_amdgcn_mfma_f32_32x32x16_f16(pA[ks], vA[ks * 2 + 1], oA1, 0, 0, 0);
    }
    __builtin_amdgcn_s_setprio(0);
    // prefetch next pair's A-tile under PACK_B/PV_B
    kp0 += 8192; vp0 += 8192;
    if (t + 2 < NKVT) { LOADF(kp0, kA); LOADF(vp0, vA); }
    // ---- PACK_B + PV_B into oB (independent of A path) ----
    f16x8 pB[2];
    PACK8(sB, 0, lsum, pB[0]); PACK8(sB, 8, lsum, pB[1]);
    __builtin_amdgcn_s_setprio(1);
    #pragma unroll
    for (int ks = 0; ks < 2; ks++) {
      oB0 = __builtin_amdgcn_mfma_f32_32x32x16_f16(pB[ks], vB_[ks * 2 + 0], oB0, 0, 0, 0);
      oB1 = __builtin_amdgcn_mfma_f32_32x32x16_f16(pB[ks], vB_[ks * 2 + 1], oB1, 0, 0, 0);
    }
    __builtin_amdgcn_s_setprio(0);
  }
#undef LOADF

  // fold parity accumulators
  f32x16 o0 = oA0 + oB0;
  f32x16 o1 = oA1 + oB1;

  // ---- merge kv halves (exact: unnormalized O and lsum add) ----
  if (kvh == 1) {
    #pragma unroll
    for (int rq = 0; rq < 4; rq++) {
      f32x4 v4;
      v4[0] = o0[rq * 4 + 0]; v4[1] = o0[rq * 4 + 1];
      v4[2] = o0[rq * 4 + 2]; v4[3] = o0[rq * 4 + 3];
      *(f32x4*)&ob[wq * 2048 + rq * 256 + lane * 4] = v4;
      f32x4 w4;
      w4[0] = o1[rq * 4 + 0]; w4[1] = o1[rq * 4 + 1];
      w4[2] = o1[rq * 4 + 2]; w4[3] = o1[rq * 4 + 3];
      *(f32x4*)&ob[wq * 2048 + (4 + rq) * 256 + lane * 4] = w4;
    }
    lb[wq * 64 + lane] = lsum;
  }
  __syncthreads();
  if (kvh == 0) {
    #pragma unroll
    for (int rq = 0; rq < 4; rq++) {
      f32x4 v4 = *(const f32x4*)&ob[wq * 2048 + rq * 256 + lane * 4];
      o0[rq * 4 + 0] += v4[0]; o0[rq * 4 + 1] += v4[1];
      o0[rq * 4 + 2] += v4[2]; o0[rq * 4 + 3] += v4[3];
      f32x4 w4 = *(const f32x4*)&ob[wq * 2048 + (4 + rq) * 256 + lane * 4];
      o1[rq * 4 + 0] += w4[0]; o1[rq * 4 + 1] += w4[1];
      o1[rq * 4 + 2] += w4[2]; o1[rq * 4 + 3] += w4[3];
    }
    lsum += lb[wq * 64 + lane];

    lsum += __shfl_xor(lsum, 32);
    float inv = 1.f / lsum;
    const int b = bh >> 4, h = bh & 15;
    #pragma unroll
    for (int reg = 0; reg < 16; reg++) {
      int qrow = (reg & 3) + 8 * (reg >> 2) + 4 * lh;
      float s = __shfl(inv, qrow);
      size_t r0 = (size_t)(b * SEQ + q0 + qrow) * DIM + h * 64;
      Od[r0 + l31]      = f2h(o0[reg] * s);
      Od[r0 + 32 + l31] = f2h(o1[reg] * s);
    }
  }
}

extern "C" void kernel_launch(void* const* d_in, const int* in_sizes, int n_in,
                              void* d_out, int out_size, void* d_ws, size_t ws_size,
                              hipStream_t stream) {
  const float* x     = (const float*)d_in[0];
  const float* Wqkv  = (const float*)d_in[1];
  const float* bqkv  = (const float*)d_in[2];
  const float* Wproj = (const float*)d_in[3];
  const float* bproj = (const float*)d_in[4];
  float* out = (float*)d_out;

  char* ws = (char*)d_ws;                       // needs 48 MB
  short* x_h    = (short*)(ws);                 //  8 MB  x as f16
  short* Wqkv_t = (short*)(ws + ((size_t)8  << 20));  // 6 MB
  short* Wproj_t= (short*)(ws + ((size_t)14 << 20));  // 2 MB
  short* Qd     = (short*)(ws + ((size_t)16 << 20));  // 8 MB (bh, n, hd)
  short* Kd     = (short*)(ws + ((size_t)24 << 20));  // 8 MB K fragment-major
  short* Vtd    = (short*)(ws + ((size_t)32 << 20));  // 8 MB V fragment-major
  short* Od     = (short*)(ws + ((size_t)40 << 20));  // 8 MB

  // 1. x -> f16
  k_cvt<<<(MROWS * DIM / 4 + 255) / 256, 256, 0, stream>>>(x, x_h, MROWS * DIM / 4);
  // 2. weights -> transposed f16 (N x K)
  dim3 tb(32, 8);
  k_transpose<<<dim3(3 * DIM / 32, DIM / 32), tb, 0, stream>>>(Wqkv, Wqkv_t, DIM, 3 * DIM);
  k_transpose<<<dim3(DIM / 32, DIM / 32), tb, 0, stream>>>(Wproj, Wproj_t, DIM, DIM);
  // 3. QKV GEMM + split/fragment epilogue (BM=128, grid 24x32, XCD-chunked)
  k_gemm_bt<0, 128><<<dim3(3 * DIM / 128, MROWS / 128), 256, 0, stream>>>(
      x_h, Wqkv_t, bqkv, Qd, Kd, Vtd, nullptr, 3 * DIM, DIM);
  // 4. flash attention (L2-direct, strength-reduced addressing)
  k_flash<<<dim3(BATCH * NH, SEQ / QBLK), 256, 0, stream>>>(Qd, Kd, Vtd, Od);
  // 5. proj GEMM -> f32 out (BM=64, grid 8x64, XCD-chunked)
  k_gemm_bt<1, 64><<<dim3(DIM / 128, MROWS / 64), 256, 0, stream>>>(
      Od, Wproj_t, bproj, nullptr, nullptr, nullptr, out, DIM, DIM);
}

// Round 20
// 130.236 us; speedup vs baseline: 1.0233x; 1.0142x over previous
//
#include <hip/hip_runtime.h>
#include <stdint.h>

#define BATCH 2
#define NH 16
#define SEQ 2048
#define DIM 1024
#define HD 64
#define MROWS (BATCH*SEQ)   // 4096

typedef __attribute__((ext_vector_type(8))) _Float16 f16x8;
typedef __attribute__((ext_vector_type(16))) float f32x16;
typedef __attribute__((ext_vector_type(4))) float f32x4;
typedef __attribute__((ext_vector_type(2))) __fp16 fp16x2;
typedef __attribute__((ext_vector_type(4))) short short4v;
typedef __attribute__((ext_vector_type(2))) unsigned uint2v;

__device__ __forceinline__ short f2h(float f) {
  union { _Float16 h; short s; } u;
  u.h = (_Float16)f;
  return u.s;
}

__device__ __forceinline__ float fast_exp2(float x) {
#if __has_builtin(__builtin_amdgcn_exp2f)
  return __builtin_amdgcn_exp2f(x);
#else
  return exp2f(x);
#endif
}

__device__ __forceinline__ unsigned pk2(float a, float b) {
  union { fp16x2 h; unsigned u; } x;
  x.h = __builtin_amdgcn_cvt_pkrtz(a, b);
  return x.u;
}

// a.hi(lanes32-63) <-> b.lo(lanes0-31).
__device__ __forceinline__ void perm32swap(unsigned &a, unsigned &b) {
#if __has_builtin(__builtin_amdgcn_permlane32_swap)
  uint2v r = __builtin_amdgcn_permlane32_swap(a, b, false, false);  // VALU op
  a = r[0]; b = r[1];
#else
  unsigned as = (unsigned)__shfl_xor((int)a, 32);
  unsigned bs = (unsigned)__shfl_xor((int)b, 32);
  bool lo = ((threadIdx.x & 63) < 32);
  unsigned na = lo ? a : bs;
  unsigned nb = lo ? as : b;
  a = na; b = nb;
#endif
}

__device__ __forceinline__ void async_load16(const void* g, void* l) {
  __builtin_amdgcn_global_load_lds((const __attribute__((address_space(1))) void*)g,
                                   (__attribute__((address_space(3))) void*)l, 16, 0, 0);
}

// ---------------- convert f32 -> f16 ----------------
__global__ __launch_bounds__(256) void k_cvt(const float* __restrict__ in,
                                             short* __restrict__ out, int n4) {
  int i = blockIdx.x * 256 + threadIdx.x;
  if (i >= n4) return;
  float4 v = ((const float4*)in)[i];
  short4v o;
  o[0] = f2h(v.x); o[1] = f2h(v.y); o[2] = f2h(v.z); o[3] = f2h(v.w);
  ((short4v*)out)[i] = o;
}

// ---------------- transpose (K x N) f32 -> (N x K) f16 ----------------
__global__ __launch_bounds__(256) void k_transpose(const float* __restrict__ in,
                                                   short* __restrict__ out,
                                                   int K, int N) {
  __shared__ float t[32][33];
  int n0 = blockIdx.x * 32, k0 = blockIdx.y * 32;
  int tx = threadIdx.x, ty = threadIdx.y;  // 32 x 8
  #pragma unroll
  for (int i = 0; i < 32; i += 8)
    t[ty + i][tx] = in[(size_t)(k0 + ty + i) * N + (n0 + tx)];
  __syncthreads();
  #pragma unroll
  for (int i = 0; i < 32; i += 8)
    out[(size_t)(n0 + ty + i) * K + (k0 + tx)] = f2h(t[tx][ty + i]);
}

// ---------------- GEMM  C[M,N] = A[M,K] * Bt[N,K]^T  (fp16 in, f32 acc) ---
// BK=64, double-buffered LDS, counted vmcnt, XOR-swizzle (rule #21 pattern),
// T1 chunked XCD block swizzle (each XCD owns a contiguous 2D tile region).
// MODE 0 (BM=128, grid 24x32): QKV epilogue; MODE 1 (BM=64, grid 8x64): f32+bias
template <int MODE, int BM>
__global__ __launch_bounds__(256) void k_gemm_bt(
    const short* __restrict__ A, const short* __restrict__ Bt,
    const float* __restrict__ bias,
    short* __restrict__ Qd, short* __restrict__ Kd, short* __restrict__ Vtd,
    float* __restrict__ Cf, int Ncols, int Kdim) {
  constexpr int BN = 128, BK = 64;
  constexpr int RI = BM / 32;            // row fragments per wave
  __shared__ short Al[2][BM * BK];
  __shared__ short Bl[2][BN * BK];
  const int tid = threadIdx.x;
  const int lane = tid & 63;
  const int wid = tid >> 6;
  const int wr = wid >> 1, wc = wid & 1;
  // T1: chunked XCD swizzle. XCD = lin%8; each XCD gets a contiguous chunk.
  const int lin = blockIdx.y * (int)gridDim.x + blockIdx.x;
  const int xcd = lin & 7, loc = lin >> 3;
  int bx, by;
  if (MODE == 0) { bx = (xcd & 1) * 12 + loc % 12; by = (xcd >> 1) * 8 + loc / 12; }
  else           { bx = loc % 8;                   by = xcd * 8 + loc / 8; }
  const int m0 = by * BM, n0 = bx * BN;
  const int l15 = lane & 15, lk = (lane >> 4) * 8;

  f32x4 acc[RI][4] = {};

  auto stage = [&](int kt, int buf) {
    int k0 = kt * BK;
    #pragma unroll
    for (int i2 = 0; i2 < BM / 32; i2++) {
      int c = i2 * 256 + tid;
      int r = c >> 3, cs = (c & 7) * 8;
      async_load16(A + (size_t)(m0 + r) * Kdim + k0 + (cs ^ ((r & 7) * 8)),
                   &Al[buf][c * 8]);
    }
    #pragma unroll
    for (int i2 = 0; i2 < 4; i2++) {
      int c = i2 * 256 + tid;
      int r = c >> 3, cs = (c & 7) * 8;
      async_load16(Bt + (size_t)(n0 + r) * Kdim + k0 + (cs ^ ((r & 7) * 8)),
                   &Bl[buf][c * 8]);
    }
  };

  auto compute = [&](int buf) {
    f16x8 af[2][RI], bfr[2][4];
    #pragma unroll
    for (int kk = 0; kk < 2; kk++) {
      #pragma unroll
      for (int i = 0; i < RI; i++) {
        int row = wr * (BM / 2) + i * 16 + l15;
        af[kk][i] = *(const f16x8*)&Al[buf][row * 64 + ((kk * 32 + lk) ^ ((row & 7) * 8))];
      }
      #pragma unroll
      for (int j = 0; j < 4; j++) {
        int row = wc * 64 + j * 16 + l15;
        bfr[kk][j] = *(const f16x8*)&Bl[buf][row * 64 + ((kk * 32 + lk) ^ ((row & 7) * 8))];
      }
    }
    __builtin_amdgcn_s_setprio(1);
    #pragma unroll
    for (int i = 0; i < RI; i++)
      #pragma unroll
      for (int j = 0; j < 4; j++) {
        acc[i][j] = __builtin_amdgcn_mfma_f32_16x16x32_f16(af[0][i], bfr[0][j], acc[i][j], 0, 0, 0);
        acc[i][j] = __builtin_amdgcn_mfma_f32_16x16x32_f16(af[1][i], bfr[1][j], acc[i][j], 0, 0, 0);
      }
    __builtin_amdgcn_s_setprio(0);
  };

  stage(0, 0);
  const int NT = Kdim / BK;
  for (int t = 0; t < NT; t++) {
    int cur = t & 1;
    if (t + 1 < NT) {
      stage(t + 1, cur ^ 1);
      if constexpr (BM == 128) asm volatile("s_waitcnt vmcnt(8)" ::: "memory");
      else                     asm volatile("s_waitcnt vmcnt(6)" ::: "memory");
    } else {
      asm volatile("s_waitcnt vmcnt(0)" ::: "memory");
    }
    __builtin_amdgcn_s_barrier();
    __builtin_amdgcn_sched_barrier(0);
    compute(cur);
    __builtin_amdgcn_sched_barrier(0);
    __builtin_amdgcn_s_barrier();
  }

  const int rl = (lane >> 4) * 4;
  if (MODE == 0) {
    #pragma unroll
    for (int j = 0; j < 4; j++) {
      int col = n0 + wc * 64 + j * 16 + l15;
      float bv = bias[col];
      int sec = col >> 10;          // 0=Q 1=K 2=V
      int cc = col & 1023;
      int h = cc >> 6, hd = cc & 63;
      float mul = (sec == 0) ? (0.125f * 1.44269504088896f) : 1.0f;
      #pragma unroll
      for (int i = 0; i < RI; i++) {
        int rowb = m0 + wr * (BM / 2) + i * 16 + rl;
        #pragma unroll
        for (int r = 0; r < 4; r++) {
          int row = rowb + r;
          int b = row >> 11, nr = row & 2047;
          short v = f2h((acc[i][j][r] + bv) * mul);
          size_t bh = (size_t)(b * NH + h);
          size_t base2 = bh * (size_t)(SEQ * HD);
          if (sec == 0) {
            Qd[base2 + (size_t)nr * HD + hd] = v;
          } else if (sec == 1) {
            // K A-frag layout
            Kd[base2 + (size_t)(((nr >> 5) * 4 + (hd >> 4)) * 512 +
                                (((hd >> 3) & 1) * 32 + (nr & 31)) * 8 + (hd & 7))] = v;
          } else {
            // V B-frag layout
            Vtd[base2 + (size_t)(((nr >> 4) * 2 + (hd >> 5)) * 512 +
                                 (((nr >> 3) & 1) * 32 + (hd & 31)) * 8 + (nr & 7))] = v;
          }
        }
      }
    }
  } else {
    #pragma unroll
    for (int j = 0; j < 4; j++) {
      int col = n0 + wc * 64 + j * 16 + l15;
      float bv = bias[col];
      #pragma unroll
      for (int i = 0; i < RI; i++) {
        int rowb = m0 + wr * (BM / 2) + i * 16 + rl;
        #pragma unroll
        for (int r = 0; r < 4; r++)
          Cf[(size_t)(rowb + r) * Ncols + col] = acc[i][j][r] + bv;
      }
    }
  }
}

// ---------------- flash attention v7 (best measured: 55.7 us) ------------
// L2-direct, no LDS main loop. K/V fragments read directly from the
// fragment-major global layouts (L2-resident); register ping-pong prefetch;
// shared o[2] accumulators (v8/v9's split-acc variant measured WORSE).
// 256 threads = 4 waves: (wq, kvh) = (q-tile, kv-half). Exact static-softmax
// merge of kv halves at kernel end via 16 KB LDS.
#define QBLK 64
#define NKVT (SEQ / 64)

#define PACK8(sv, R0, lsv, OUT) do {                                        \
    float e0_ = fast_exp2((sv)[R0 + 0]), e1_ = fast_exp2((sv)[R0 + 1]);     \
    float e2_ = fast_exp2((sv)[R0 + 2]), e3_ = fast_exp2((sv)[R0 + 3]);     \
    float e4_ = fast_exp2((sv)[R0 + 4]), e5_ = fast_exp2((sv)[R0 + 5]);     \
    float e6_ = fast_exp2((sv)[R0 + 6]), e7_ = fast_exp2((sv)[R0 + 7]);     \
    lsv += ((e0_ + e1_) + (e2_ + e3_)) + ((e4_ + e5_) + (e6_ + e7_));       \
    unsigned u0_ = pk2(e0_, e1_), u1_ = pk2(e2_, e3_);                      \
    unsigned u2_ = pk2(e4_, e5_), u3_ = pk2(e6_, e7_);                      \
    perm32swap(u0_, u2_);                                                   \
    perm32swap(u1_, u3_);                                                   \
    union { unsigned u[4]; f16x8 v; } W_;                                   \
    W_.u[0] = u0_; W_.u[1] = u1_; W_.u[2] = u2_; W_.u[3] = u3_;             \
    OUT = W_.v;                                                             \
  } while (0)

__global__ __launch_bounds__(256) void k_flash(const short* __restrict__ Qd,
                                               const short* __restrict__ KB,
                                               const short* __restrict__ VB,
                                               short* __restrict__ Od) {
  __shared__ float ob[4096];   // merge: 2 q-tiles x 2048 floats (16 KB)
  __shared__ float lb[128];
  const int tid = threadIdx.x;
  const int lane = tid & 63;
  const int w = tid >> 6;
  const int wq = w >> 1;             // q-tile within block (0,1)
  const int kvh = w & 1;             // kv half of each tile (0,1)
  const int l31 = lane & 31, lh = lane >> 5;
  const int bh = blockIdx.x;
  const int q0 = blockIdx.y * QBLK + wq * 32;
  const size_t base = (size_t)bh * (size_t)(SEQ * HD);

  // Q fragments (B-operand): col q = l31, k = d = ds*16 + lh*8 + i
  f16x8 qf[4];
  #pragma unroll
  for (int ds = 0; ds < 4; ds++)
    qf[ds] = *(const f16x8*)(Qd + base + (size_t)(q0 + l31) * HD + ds * 16 + lh * 8);

  // wave-uniform fragment bases (this wave's kv-half folded in)
  const short* kb = KB + base + kvh * 2048 + (size_t)lane * 8;
  const short* vb = VB + base + kvh * 2048 + (size_t)lane * 8;

  f32x16 o[2] = {};          // [hdt] partial over this wave's kv set
  float lsum = 0.f;

  // load K fragment set for tile t (4 x dwordx4, imm offsets 0..3072B)
#define LOADK(t, kf) do {                                                   \
    const short* p_ = kb + (size_t)(t) * 4096;                              \
    kf[0] = *(const f16x8*)(p_);                                            \
    kf[1] = *(const f16x8*)(p_ + 512);                                      \
    kf[2] = *(const f16x8*)(p_ + 1024);                                     \
    kf[3] = *(const f16x8*)(p_ + 1536);                                     \
  } while (0)
#define LOADV(t, vf) do {                                                   \
    const short* p_ = vb + (size_t)(t) * 4096;                              \
    vf[0] = *(const f16x8*)(p_);            /* ks0 hd0 */                   \
    vf[1] = *(const f16x8*)(p_ + 512);      /* ks0 hd1 */                   \
    vf[2] = *(const f16x8*)(p_ + 1024);     /* ks1 hd0 */                   \
    vf[3] = *(const f16x8*)(p_ + 1536);     /* ks1 hd1 */                   \
  } while (0)

  auto compute = [&](const f16x8* kf, const f16x8* vf) {
    f32x16 s = {};             // 32 kv (this half) x 32 q
    __builtin_amdgcn_s_setprio(1);
    #pragma unroll
    for (int ds = 0; ds < 4; ds++)
      s = __builtin_amdgcn_mfma_f32_32x32x16_f16(kf[ds], qf[ds], s, 0, 0, 0);
    __builtin_amdgcn_s_setprio(0);
    f16x8 p[2];
    PACK8(s, 0, lsum, p[0]); PACK8(s, 8, lsum, p[1]);
    __builtin_amdgcn_s_setprio(1);
    #pragma unroll
    for (int ks = 0; ks < 2; ks++) {
      o[0] = __builtin_amdgcn_mfma_f32_32x32x16_f16(p[ks], vf[ks * 2 + 0], o[0], 0, 0, 0);
      o[1] = __builtin_amdgcn_mfma_f32_32x32x16_f16(p[ks], vf[ks * 2 + 1], o[1], 0, 0, 0);
    }
    __builtin_amdgcn_s_setprio(0);
  };

  f16x8 kA[4], vA[4], kB_[4], vB_[4];
  LOADK(0, kA); LOADV(0, vA);
  for (int t = 0; t < NKVT; t += 2) {
    if (t + 1 < NKVT) { LOADK(t + 1, kB_); LOADV(t + 1, vB_); }
    compute(kA, vA);
    if (t + 2 < NKVT) { LOADK(t + 2, kA); LOADV(t + 2, vA); }
    if (t + 1 < NKVT) compute(kB_, vB_);
  }
#undef LOADK
#undef LOADV

  // ---- merge kv halves (exact: unnormalized O and lsum add) ----
  if (kvh == 1) {
    #pragma unroll
    for (int hdt = 0; hdt < 2; hdt++)
      #pragma unroll
      for (int rq = 0; rq < 4; rq++) {
        f32x4 v4;
        v4[0] = o[hdt][rq * 4 + 0]; v4[1] = o[hdt][rq * 4 + 1];
        v4[2] = o[hdt][rq * 4 + 2]; v4[3] = o[hdt][rq * 4 + 3];
        *(f32x4*)&ob[wq * 2048 + (hdt * 4 + rq) * 256 + lane * 4] = v4;
      }
    lb[wq * 64 + lane] = lsum;
  }
  __syncthreads();
  if (kvh == 0) {
    #pragma unroll
    for (int hdt = 0; hdt < 2; hdt++)
      #pragma unroll
      for (int rq = 0; rq < 4; rq++) {
        f32x4 v4 = *(const f32x4*)&ob[wq * 2048 + (hdt * 4 + rq) * 256 + lane * 4];
        o[hdt][rq * 4 + 0] += v4[0]; o[hdt][rq * 4 + 1] += v4[1];
        o[hdt][rq * 4 + 2] += v4[2]; o[hdt][rq * 4 + 3] += v4[3];
      }
    lsum += lb[wq * 64 + lane];

    lsum += __shfl_xor(lsum, 32);
    float inv = 1.f / lsum;
    const int b = bh >> 4, h = bh & 15;
    #pragma unroll
    for (int reg = 0; reg < 16; reg++) {
      int qrow = (reg & 3) + 8 * (reg >> 2) + 4 * lh;
      float s = __shfl(inv, qrow);
      size_t r0 = (size_t)(b * SEQ + q0 + qrow) * DIM + h * 64;
      Od[r0 + l31]      = f2h(o[0][reg] * s);
      Od[r0 + 32 + l31] = f2h(o[1][reg] * s);
    }
  }
}

extern "C" void kernel_launch(void* const* d_in, const int* in_sizes, int n_in,
                              void* d_out, int out_size, void* d_ws, size_t ws_size,
                              hipStream_t stream) {
  const float* x     = (const float*)d_in[0];
  const float* Wqkv  = (const float*)d_in[1];
  const float* bqkv  = (const float*)d_in[2];
  const float* Wproj = (const float*)d_in[3];
  const float* bproj = (const float*)d_in[4];
  float* out = (float*)d_out;

  char* ws = (char*)d_ws;                       // needs 48 MB
  short* x_h    = (short*)(ws);                 //  8 MB  x as f16
  short* Wqkv_t = (short*)(ws + ((size_t)8  << 20));  // 6 MB
  short* Wproj_t= (short*)(ws + ((size_t)14 << 20));  // 2 MB
  short* Qd     = (short*)(ws + ((size_t)16 << 20));  // 8 MB (bh, n, hd)
  short* Kd     = (short*)(ws + ((size_t)24 << 20));  // 8 MB K fragment-major
  short* Vtd    = (short*)(ws + ((size_t)32 << 20));  // 8 MB V fragment-major
  short* Od     = (short*)(ws + ((size_t)40 << 20));  // 8 MB

  // 1. x -> f16
  k_cvt<<<(MROWS * DIM / 4 + 255) / 256, 256, 0, stream>>>(x, x_h, MROWS * DIM / 4);
  // 2. weights -> transposed f16 (N x K)
  dim3 tb(32, 8);
  k_transpose<<<dim3(3 * DIM / 32, DIM / 32), tb, 0, stream>>>(Wqkv, Wqkv_t, DIM, 3 * DIM);
  k_transpose<<<dim3(DIM / 32, DIM / 32), tb, 0, stream>>>(Wproj, Wproj_t, DIM, DIM);
  // 3. QKV GEMM + split/fragment epilogue (BM=128, grid 24x32, XCD-chunked)
  k_gemm_bt<0, 128><<<dim3(3 * DIM / 128, MROWS / 128), 256, 0, stream>>>(
      x_h, Wqkv_t, bqkv, Qd, Kd, Vtd, nullptr, 3 * DIM, DIM);
  // 4. flash attention (L2-direct v7, 1024 blocks)
  k_flash<<<dim3(BATCH * NH, SEQ / QBLK), 256, 0, stream>>>(Qd, Kd, Vtd, Od);
  // 5. proj GEMM -> f32 out (BM=64, grid 8x64, XCD-chunked)
  k_gemm_bt<1, 64><<<dim3(DIM / 128, MROWS / 64), 256, 0, stream>>>(
      Od, Wproj_t, bproj, nullptr, nullptr, nullptr, out, DIM, DIM);
}